// Round 1
// 171.306 us; speedup vs baseline: 1.0633x; 1.0633x over previous
//
#include <hip/hip_runtime.h>

#define B_TOT 8192
#define NB    16         // batch elements per block
#define NPCS  20

typedef __attribute__((ext_vector_type(8))) __fp16 f16x8;
typedef __attribute__((ext_vector_type(4))) float f32x4;
typedef __attribute__((ext_vector_type(2))) __fp16 fp16x2;

__device__ __forceinline__ unsigned pkmax(unsigned a, unsigned b) {
    unsigned d; asm("v_pk_max_f16 %0, %1, %2" : "=v"(d) : "v"(a), "v"(b)); return d;
}
__device__ __forceinline__ unsigned pkmin(unsigned a, unsigned b) {
    unsigned d; asm("v_pk_min_f16 %0, %1, %2" : "=v"(d) : "v"(a), "v"(b)); return d;
}
__device__ __forceinline__ float h2f(unsigned u) {   // converts low 16 bits
    float f; asm("v_cvt_f32_f16 %0, %1" : "=v"(f) : "v"(u)); return f;
}
// RNE f16 pack via compiler-generated casts (default FP rounding = RNE)
__device__ __forceinline__ unsigned pkrne(float a, float b) {
    fp16x2 h;
    h.x = (__fp16)a;
    h.y = (__fp16)b;
    return __builtin_bit_cast(unsigned, h);
}
__device__ __forceinline__ float asf(unsigned u) { return __builtin_bit_cast(float, u); }
__device__ __forceinline__ unsigned asu(float f) { return __builtin_bit_cast(unsigned, f); }
__device__ __forceinline__ fp16x2 ash2(unsigned u) { return __builtin_bit_cast(fp16x2, u); }
__device__ __forceinline__ unsigned asu2(fp16x2 h) { return __builtin_bit_cast(unsigned, h); }

// lane-xor exchange within 16-lane DPP rows; lm constant-folded in unrolled loops.
template<int CTRL>
__device__ __forceinline__ unsigned dppmov(unsigned v) {
    return (unsigned)__builtin_amdgcn_mov_dpp((int)v, CTRL, 0xf, 0xf, true);
}
__device__ __forceinline__ unsigned xlane(unsigned v, int lm) {
    switch (lm) {
    case 1:  return dppmov<0xB1>(v);    // quad_perm [1,0,3,2]  = xor 1
    case 2:  return dppmov<0x4E>(v);    // quad_perm [2,3,0,1]  = xor 2
    case 4:  return (unsigned)__builtin_amdgcn_ds_swizzle((int)v, 0x101F); // xor 4
    default: return dppmov<0x128>(v);   // row_ror:8 == xor 8 within 16-lane row
    }
}
__device__ __forceinline__ float xlanef(float v, int lm) { return asf(xlane(asu(v), lm)); }

// ---------------- d_ws layout (bytes) ----------------
// [0,     32768): W2T f16 [128][128]   w2t[j*128+k] = f16(W2[k][j])
// [32768, 40960): W3T f16 [32][128]    w3t[c*128+k] = f16(W3[k][c])
// [40960, 57344): wsp f32  [32][128]   precomputed fspool weights
// [57344, 59392): w1d u32 [128][4]     dup-f16 pair (w,w) of W1[k][h]
// [59392, 59904): b1d u32 [128]        dup-f16 pair (b,b) of b1[h]
#define WS_W3T 32768
#define WS_WSP 40960
#define WS_W1D 57344
#define WS_B1D 59392

__device__ __forceinline__ unsigned dup16(float f) {
    unsigned short u = __builtin_bit_cast(unsigned short, (__fp16)f);
    return (unsigned)u * 0x10001u;
}

__global__ void prep_kernel(const float* __restrict__ W1, const float* __restrict__ b1,
                            const float* __restrict__ W2, const float* __restrict__ W3,
                            const float* __restrict__ pw, void* __restrict__ ws)
{
    const int t = blockIdx.x * 256 + threadIdx.x;
    __fp16* w2t = (__fp16*)ws;
    __fp16* w3t = (__fp16*)((char*)ws + WS_W3T);
    float* wsp  = (float*)((char*)ws + WS_WSP);
    unsigned* w1d = (unsigned*)((char*)ws + WS_W1D);
    unsigned* b1d = (unsigned*)((char*)ws + WS_B1D);
    if (t < 16384) {
        int j = t >> 7, k = t & 127;
        w2t[t] = (__fp16)W2[k * 128 + j];
    } else if (t < 20480) {
        int o = t - 16384, c = o >> 7, k = o & 127;
        w3t[o] = (__fp16)W3[k * 32 + c];
    } else if (t < 24576) {
        int o = t - 20480, c = o >> 7, p = o & 127;
        float pos = (float)p * (20.0f / 127.0f);
        int ip = min((int)pos, NPCS);
        float fr = pos - (float)ip;
        int ipb = min(ip + 1, NPCS);
        wsp[o] = (1.0f - fr) * pw[c * 21 + ip] + fr * pw[c * 21 + ipb];
    } else if (t < 24704) {
        int h = t - 24576;
        w1d[h * 4 + 0] = dup16(W1[h]);
        w1d[h * 4 + 1] = dup16(W1[128 + h]);
        w1d[h * 4 + 2] = dup16(W1[256 + h]);
        w1d[h * 4 + 3] = dup16(W1[384 + h]);
        b1d[h] = dup16(b1[h]);
    }
}

// ---------------- LDS layout (bytes, total 63232) ----------------
// [0,     32768): sW2T f16, rows 256 B, chunk phys = ch ^ (row&15)  (xor swizzle)
// [32768, 50176): scr  f16, per-wave 16 x 136 halfs
// [50176, 58624): szp  uint [16][132]  packed-f16 z pairs
// [58624, 60672): sw1d u32 [128][4]  dup-f16 W1
// [60672, 61184): sb1d u32 [128]     dup-f16 b1
// [61184, 63232): spool f32[NB*32]
#define L_SCR  32768
#define L_SZP  50176
#define L_W1D  58624
#define L_B1D  60672
#define L_POOL 61184

__global__ __launch_bounds__(256, 2) void enc_kernel(
    const float* __restrict__ x,   const float* __restrict__ b1g,
    const float* __restrict__ b2g, const float* __restrict__ b3g,
    const float* __restrict__ eps, const void* __restrict__ ws,
    float* __restrict__ out)
{
    __shared__ __align__(16) char smem[63232];

    const int tid  = threadIdx.x;
    const int wv   = tid >> 6;
    const int lane = tid & 63;
    const int l16  = lane & 15;     // lane-within-group for the sort
    const int quad = lane >> 4;
    const int b0   = blockIdx.x * NB;

    // ---------- stage sW2T (xor-swizzled), w1d+b1d ----------
    {
        const uint4* src = (const uint4*)ws;     // 2048 16B chunks
#pragma unroll
        for (int it = 0; it < 8; ++it) {
            int idx = tid + it * 256;
            int j = idx >> 4, ch = idx & 15;
            *(uint4*)(smem + j * 256 + ((ch ^ (j & 15)) * 16)) = src[idx];
        }
    }
    if (tid < 160) ((uint4*)(smem + L_W1D))[tid] = ((const uint4*)((const char*)ws + WS_W1D))[tid];

    // ---------- hoisted register-resident data (persist across NB elements) ----------
    f16x8 w3f[2][4];                                   // W3T A-frags
    {
        const __fp16* w3t = (const __fp16*)((const char*)ws + WS_W3T);
#pragma unroll
        for (int mt2 = 0; mt2 < 2; ++mt2)
#pragma unroll
            for (int kt = 0; kt < 4; ++kt)
                w3f[mt2][kt] = *(const f16x8*)(w3t + (mt2 * 16 + l16) * 128 + kt * 32 + quad * 8);
    }
    float4 b3v[2];
    b3v[0] = *(const float4*)(b3g + quad * 4);
    b3v[1] = *(const float4*)(b3g + 16 + quad * 4);
    float b2r[8];
#pragma unroll
    for (int nt = 0; nt < 8; ++nt) b2r[nt] = b2g[nt * 16 + l16];

    // fspool weights for this lane's pair-row (element-invariant)
    const int pr = wv * 4 + quad;    // packed pair-row: channels 2pr (mu), 2pr+1 (logvar)
    float wE[8], wO[8];
    {
        const float* wsp = (const float*)((const char*)ws + WS_WSP);
        float4 e0 = *(const float4*)(wsp + (2 * pr) * 128 + l16 * 8);
        float4 e1 = *(const float4*)(wsp + (2 * pr) * 128 + l16 * 8 + 4);
        float4 o0 = *(const float4*)(wsp + (2 * pr + 1) * 128 + l16 * 8);
        float4 o1 = *(const float4*)(wsp + (2 * pr + 1) * 128 + l16 * 8 + 4);
        wE[0]=e0.x; wE[1]=e0.y; wE[2]=e0.z; wE[3]=e0.w; wE[4]=e1.x; wE[5]=e1.y; wE[6]=e1.z; wE[7]=e1.w;
        wO[0]=o0.x; wO[1]=o0.y; wO[2]=o0.z; wO[3]=o0.w; wO[4]=o1.x; wO[5]=o1.y; wO[6]=o1.z; wO[7]=o1.w;
    }
    __syncthreads();

    __fp16*   scr   = (__fp16*)(smem + L_SCR) + wv * (16 * 136);
    unsigned* szp   = (unsigned*)(smem + L_SZP);       // stride 132
    float*    spool = (float*)(smem + L_POOL);

    // x prefetch: element 0 loaded ahead of the loop
    const float* xptr = x + (size_t)b0 * 512 + (wv * 32 + l16) * 4;
    float4 xv0 = *(const float4*)(xptr);
    float4 xv1 = *(const float4*)(xptr + 64);

    for (int e = 0; e < NB; ++e) {
        // ---------- GEMM1 (packed f16 VALU, K=4): rows (xv0,xv1) share pk halves ----------
        fp16x2 xh[4];
        xh[0].x = (__fp16)xv0.x; xh[0].y = (__fp16)xv1.x;
        xh[1].x = (__fp16)xv0.y; xh[1].y = (__fp16)xv1.y;
        xh[2].x = (__fp16)xv0.z; xh[2].y = (__fp16)xv1.z;
        xh[3].x = (__fp16)xv0.w; xh[3].y = (__fp16)xv1.w;

        // prefetch next element's x (consumed next iteration; hides HBM latency)
        if (e + 1 < NB) {
            xv0 = *(const float4*)(xptr + (e + 1) * 512);
            xv1 = *(const float4*)(xptr + (e + 1) * 512 + 64);
        }

        union AF { unsigned u[4]; f16x8 v; } a1[2][4];
#pragma unroll
        for (int kt = 0; kt < 4; ++kt) {
            const int k8 = kt * 32 + quad * 8;
#pragma unroll
            for (int jp = 0; jp < 4; ++jp) {
                const int h = k8 + 2 * jp;
                const uint4 wa = *(const uint4*)(smem + L_W1D + h * 16);        // dup pairs for h
                const uint4 wb = *(const uint4*)(smem + L_W1D + h * 16 + 16);   // dup pairs for h+1
                const uint2 bp = *(const uint2*)(smem + L_B1D + h * 4);         // dup bias h, h+1
                fp16x2 accA = ash2(bp.x);
                fp16x2 accB = ash2(bp.y);
                accA = __builtin_elementwise_fma(xh[0], ash2(wa.x), accA);
                accA = __builtin_elementwise_fma(xh[1], ash2(wa.y), accA);
                accA = __builtin_elementwise_fma(xh[2], ash2(wa.z), accA);
                accA = __builtin_elementwise_fma(xh[3], ash2(wa.w), accA);
                accB = __builtin_elementwise_fma(xh[0], ash2(wb.x), accB);
                accB = __builtin_elementwise_fma(xh[1], ash2(wb.y), accB);
                accB = __builtin_elementwise_fma(xh[2], ash2(wb.z), accB);
                accB = __builtin_elementwise_fma(xh[3], ash2(wb.w), accB);
                const unsigned uA = pkmax(asu2(accA), 0u);   // relu, packed
                const unsigned uB = pkmax(asu2(accB), 0u);
                // accA=(rA_h,rB_h), accB=(rA_h1,rB_h1) -> frag mt0=(rA_h,rA_h1), mt1=(rB_h,rB_h1)
                a1[0][kt].u[jp] = __builtin_amdgcn_perm(uA, uB, 0x01000504u);
                a1[1][kt].u[jp] = __builtin_amdgcn_perm(uA, uB, 0x03020706u);
            }
        }

        // ---------- GEMM2 (MFMA f16): h2 = relu(h1 @ W2 + b2), bias pre-seeded ----------
        f32x4 acc2[2][8];
#pragma unroll
        for (int mt = 0; mt < 2; ++mt)
#pragma unroll
            for (int nt = 0; nt < 8; ++nt)
                acc2[mt][nt] = (f32x4){b2r[nt], b2r[nt], b2r[nt], b2r[nt]};
#pragma unroll
        for (int kt = 0; kt < 4; ++kt)
#pragma unroll
            for (int nt = 0; nt < 8; ++nt) {
                const int j = nt * 16 + l16;
                const int phys = (kt * 4 + quad) ^ l16;
                f16x8 bf = *(const f16x8*)(smem + j * 256 + phys * 16);
                acc2[0][nt] = __builtin_amdgcn_mfma_f32_16x16x32_f16(a1[0][kt].v, bf, acc2[0][nt], 0, 0, 0);
                acc2[1][nt] = __builtin_amdgcn_mfma_f32_16x16x32_f16(a1[1][kt].v, bf, acc2[1][nt], 0, 0, 0);
            }

        // ---------- GEMM3 transposed: z = W3T @ h2^T (+b3), via per-wave scr ----------
#pragma unroll
        for (int mt = 0; mt < 2; ++mt) {
#pragma unroll
            for (int nt = 0; nt < 8; ++nt) {
                const int col = nt * 16 + l16;
#pragma unroll
                for (int r = 0; r < 4; ++r)
                    scr[(quad * 4 + r) * 136 + col] = (__fp16)fmaxf(acc2[mt][nt][r], 0.0f);  // HW RNE cvt
            }
            asm volatile("s_waitcnt lgkmcnt(0)" ::: "memory");  // wave-local scr RAW

            f16x8 a3[4];
#pragma unroll
            for (int kt = 0; kt < 4; ++kt)
                a3[kt] = *(const f16x8*)(scr + l16 * 136 + kt * 32 + quad * 8);

            const int colbase = wv * 32 + mt * 16;
#pragma unroll
            for (int mt2 = 0; mt2 < 2; ++mt2) {
                f32x4 acc = (f32x4){b3v[mt2].x, b3v[mt2].y, b3v[mt2].z, b3v[mt2].w};
#pragma unroll
                for (int kt = 0; kt < 4; ++kt)
                    acc = __builtin_amdgcn_mfma_f32_16x16x32_f16(w3f[mt2][kt], a3[kt], acc, 0, 0, 0);
                // lane holds z rows c = 16*mt2 + 4*quad + r, col p = colbase + l16
                const int prw = 8 * mt2 + 2 * quad;
                szp[prw * 132 + colbase + l16]       = pkrne(acc[0], acc[1]);  // RNE; lo=even c (mu)
                szp[(prw + 1) * 132 + colbase + l16] = pkrne(acc[2], acc[3]);
            }
            asm volatile("" ::: "memory");  // keep a3 reads ahead of next-mt scr writes
        }
        __syncthreads();  // all waves' z columns visible

        // ---------- packed-f16 bitonic sort, 8 elems/lane over 16-lane groups ----------
        // group = quad; virtual element index i = l16*8 + r; full sort => input order free
        unsigned v[8];
        {
            const unsigned* zp = szp + pr * 132 + l16 * 8;
            uint4 za = *(const uint4*)zp;
            uint4 zb = *(const uint4*)(zp + 4);
            v[0]=za.x; v[1]=za.y; v[2]=za.z; v[3]=za.w;
            v[4]=zb.x; v[5]=zb.y; v[6]=zb.z; v[7]=zb.w;
        }
        const int ib = l16 * 8;
#pragma unroll
        for (int k = 2; k <= 128; k <<= 1) {
#pragma unroll
            for (int j = 64; j >= 1; j >>= 1) {
                if (j >= k) continue;
                if (j >= 8) {                       // cross-lane (within 16-lane DPP row)
                    const bool km = ((ib & k) == 0) != ((ib & j) != 0);
                    const int lm = j >> 3;
#pragma unroll
                    for (int r = 0; r < 8; ++r) {
                        unsigned p = xlane(v[r], lm);
                        unsigned mx = pkmax(v[r], p), mn = pkmin(v[r], p);
                        v[r] = km ? mx : mn;
                    }
                } else if (k <= 4) {                // in-lane, static direction
#pragma unroll
                    for (int a = 0; a < 8; ++a) {
                        if (a & j) continue;
                        const int bx = a | j;
                        unsigned mx = pkmax(v[a], v[bx]), mn = pkmin(v[a], v[bx]);
                        if ((a & k) == 0) { v[a] = mx; v[bx] = mn; }
                        else              { v[a] = mn; v[bx] = mx; }
                    }
                } else {                            // in-lane, lane-dependent direction
                    const bool km = ((ib & k) == 0);
#pragma unroll
                    for (int a = 0; a < 8; ++a) {
                        if (a & j) continue;
                        const int bx = a | j;
                        unsigned mx = pkmax(v[a], v[bx]), mn = pkmin(v[a], v[bx]);
                        v[a] = km ? mx : mn;
                        v[bx] = km ? mn : mx;
                    }
                }
            }
        }

        // ---------- weighted sum + 16-lane group reduction (DPP) ----------
        float sE = 0.f, sO = 0.f;
#pragma unroll
        for (int r = 0; r < 8; ++r) {
            sE = fmaf(wE[r], h2f(v[r]), sE);
            sO = fmaf(wO[r], h2f(v[r] >> 16), sO);
        }
#pragma unroll
        for (int d = 8; d >= 1; d >>= 1) {
            sE += xlanef(sE, d);
            sO += xlanef(sO, d);
        }
        if (l16 == 0) {
            spool[e * 32 + 2 * pr]     = sE;
            spool[e * 32 + 2 * pr + 1] = sO;
        }
        __syncthreads();  // spool ready; protects szp WAR for next element
    }

    // ---------- batched coalesced epilogue (NB*16 == 256) ----------
    {
        const int e = tid >> 4, t = tid & 15;
        const float mu = spool[e * 32 + 2 * t];
        const float lv = spool[e * 32 + 2 * t + 1];
        const float ev = eps[(size_t)b0 * 16 + tid];
        const float smp = fmaf(ev, __expf(0.5f * lv), mu);
        out[(size_t)b0 * 16 + tid] = mu;
        out[(size_t)B_TOT * 16 + (size_t)b0 * 16 + tid] = lv;
        out[(size_t)2 * B_TOT * 16 + (size_t)b0 * 16 + tid] = smp;
    }
}

extern "C" void kernel_launch(void* const* d_in, const int* in_sizes, int n_in,
                              void* d_out, int out_size, void* d_ws, size_t ws_size,
                              hipStream_t stream) {
    const float* x   = (const float*)d_in[0];
    const float* W1  = (const float*)d_in[1];
    const float* b1  = (const float*)d_in[2];
    const float* W2  = (const float*)d_in[3];
    const float* b2  = (const float*)d_in[4];
    const float* W3  = (const float*)d_in[5];
    const float* b3  = (const float*)d_in[6];
    const float* pw  = (const float*)d_in[7];
    const float* eps = (const float*)d_in[8];
    float* out = (float*)d_out;

    prep_kernel<<<dim3(97), dim3(256), 0, stream>>>(W1, b1, W2, W3, pw, d_ws);
    enc_kernel<<<dim3(B_TOT / NB), dim3(256), 0, stream>>>(x, b1, b2, b3, eps, d_ws, out);
}